// Round 1
// baseline (236.995 us; speedup 1.0000x reference)
//
#include <hip/hip_runtime.h>
#include <hip/hip_bf16.h>
#include <stdint.h>

typedef __bf16 bf16x8 __attribute__((ext_vector_type(8)));
typedef float  f32x4  __attribute__((ext_vector_type(4)));

#define B_   2
#define T_   2048
#define H_   16
#define DH_  64
#define DM_  1024
#define BH_  (B_*H_)   // 32
#define M_   (B_*T_)   // 4096

// ---- async global->LDS, 16B per lane; LDS dest must be wave-uniform base ----
static __device__ __forceinline__ void gload_lds16(const void* g, void* lds) {
  __builtin_amdgcn_global_load_lds(
      (const __attribute__((address_space(1))) void*)(uintptr_t)g,
      (__attribute__((address_space(3))) void*)(uint32_t)(uintptr_t)lds,
      16, 0, 0);
}

// ---------------- conversion kernels ----------------
__global__ void k_cvt_bf16(const float* __restrict__ in, __hip_bfloat16* __restrict__ out, int n4) {
  int i = blockIdx.x * blockDim.x + threadIdx.x;
  if (i < n4) {
    float4 v = reinterpret_cast<const float4*>(in)[i];
    alignas(8) __hip_bfloat16 t[4] = {__float2bfloat16(v.x), __float2bfloat16(v.y),
                                      __float2bfloat16(v.z), __float2bfloat16(v.w)};
    reinterpret_cast<uint2*>(out)[i] = *reinterpret_cast<const uint2*>(t);
  }
}

// in [K][N] f32 row-major -> out [N][K] bf16 row-major (B^T for gemm_bt)
__global__ void k_cvtT(const float* __restrict__ in, __hip_bfloat16* __restrict__ out, int K, int N) {
  __shared__ float tile[32][33];
  int n0 = blockIdx.x * 32, k0 = blockIdx.y * 32;
  int tid = threadIdx.x;
  int kl = tid >> 3, n4 = (tid & 7) * 4;
  float4 v = *reinterpret_cast<const float4*>(in + (size_t)(k0 + kl) * N + n0 + n4);
  tile[kl][n4 + 0] = v.x; tile[kl][n4 + 1] = v.y; tile[kl][n4 + 2] = v.z; tile[kl][n4 + 3] = v.w;
  __syncthreads();
  int nl = tid >> 3, k4 = (tid & 7) * 4;
  alignas(8) __hip_bfloat16 t[4];
  #pragma unroll
  for (int j = 0; j < 4; ++j) t[j] = __float2bfloat16(tile[k4 + j][nl]);
  *reinterpret_cast<uint2*>(out + (size_t)(n0 + nl) * K + k0 + k4) = *reinterpret_cast<const uint2*>(t);
}

// v_in [BH][T][DH] -> v_out [BH][DH][T]
__global__ void k_transposeV(const __hip_bfloat16* __restrict__ v_in, __hip_bfloat16* __restrict__ v_out) {
  int bh = blockIdx.y;
  int idx = blockIdx.x * blockDim.x + threadIdx.x;  // 0 .. 64*256-1
  int dh = idx >> 8;
  int t8 = (idx & 255) * 8;
  const __hip_bfloat16* src = v_in + ((size_t)bh * T_ + t8) * DH_ + dh;
  alignas(16) __hip_bfloat16 t[8];
  #pragma unroll
  for (int j = 0; j < 8; ++j) t[j] = src[(size_t)j * DH_];
  *reinterpret_cast<uint4*>(v_out + ((size_t)bh * DH_ + dh) * T_ + t8) =
      *reinterpret_cast<const uint4*>(t);
}

// ---------------- 128x128 bf16 GEMM core (B^T input), BK=32 ----------------
static __device__ __forceinline__ void gemm_core_128(
    const __hip_bfloat16* __restrict__ A, const __hip_bfloat16* __restrict__ BT,
    int K, int brow, int bcol, __hip_bfloat16* As, __hip_bfloat16* Bs, f32x4 acc[4][4]) {
  const int tid = threadIdx.x, wave = tid >> 6, lane = tid & 63;
  const int wr = wave >> 1, wc = wave & 1;
  const int llo = lane & 15, lhi = lane >> 4;
  for (int k0 = 0; k0 < K; k0 += 32) {
    #pragma unroll
    for (int p = 0; p < 2; ++p) {
      int rb = p * 64 + wave * 16;
      gload_lds16(A  + (size_t)(brow + rb + (lane >> 2)) * K + k0 + (lane & 3) * 8, As + rb * 32);
      gload_lds16(BT + (size_t)(bcol + rb + (lane >> 2)) * K + k0 + (lane & 3) * 8, Bs + rb * 32);
    }
    __syncthreads();
    bf16x8 a[4], b[4];
    #pragma unroll
    for (int i = 0; i < 4; ++i)
      a[i] = *reinterpret_cast<const bf16x8*>(As + (wr * 64 + i * 16 + llo) * 32 + lhi * 8);
    #pragma unroll
    for (int j = 0; j < 4; ++j)
      b[j] = *reinterpret_cast<const bf16x8*>(Bs + (wc * 64 + j * 16 + llo) * 32 + lhi * 8);
    #pragma unroll
    for (int i = 0; i < 4; ++i)
      #pragma unroll
      for (int j = 0; j < 4; ++j)
        acc[i][j] = __builtin_amdgcn_mfma_f32_16x16x32_bf16(a[i], b[j], acc[i][j], 0, 0, 0);
    __syncthreads();
  }
}

// GEMM1: qkv = xb @ w_qkv ; scatter into Q [bh][t][dh], K [bh][t][dh], Vtmp [bh][t][dh]
__global__ __launch_bounds__(256) void k_gemm_qkv(
    const __hip_bfloat16* __restrict__ A, const __hip_bfloat16* __restrict__ BT,
    __hip_bfloat16* __restrict__ q_ws, __hip_bfloat16* __restrict__ k_ws,
    __hip_bfloat16* __restrict__ v_ws) {
  alignas(16) __shared__ __hip_bfloat16 As[128 * 32];
  alignas(16) __shared__ __hip_bfloat16 Bs[128 * 32];
  f32x4 acc[4][4] = {};
  const int brow = blockIdx.y * 128, bcol = blockIdx.x * 128;
  gemm_core_128(A, BT, DM_, brow, bcol, As, Bs, acc);
  const int tid = threadIdx.x, wave = tid >> 6, lane = tid & 63;
  const int wr = wave >> 1, wc = wave & 1;
  const int llo = lane & 15, lhi = lane >> 4;
  #pragma unroll
  for (int i = 0; i < 4; ++i) {
    #pragma unroll
    for (int j = 0; j < 4; ++j) {
      int n = bcol + wc * 64 + j * 16 + llo;
      int part = n >> 10, rem = n & 1023, hh = rem >> 6, dh = rem & 63;
      #pragma unroll
      for (int r = 0; r < 4; ++r) {
        int m = brow + wr * 64 + i * 16 + lhi * 4 + r;
        int b = m >> 11, t = m & 2047;
        __hip_bfloat16 val = __float2bfloat16(acc[i][j][r]);
        size_t idx = (((size_t)(b * H_ + hh)) * T_ + t) * DH_ + dh;
        if (part == 0)      q_ws[idx] = val;
        else if (part == 1) k_ws[idx] = val;
        else                v_ws[idx] = val;
      }
    }
  }
}

// GEMM2: out = y @ w_out (f32 output)
__global__ __launch_bounds__(256) void k_gemm_out(
    const __hip_bfloat16* __restrict__ A, const __hip_bfloat16* __restrict__ BT,
    float* __restrict__ C) {
  alignas(16) __shared__ __hip_bfloat16 As[128 * 32];
  alignas(16) __shared__ __hip_bfloat16 Bs[128 * 32];
  f32x4 acc[4][4] = {};
  const int brow = blockIdx.y * 128, bcol = blockIdx.x * 128;
  gemm_core_128(A, BT, DM_, brow, bcol, As, Bs, acc);
  const int tid = threadIdx.x, wave = tid >> 6, lane = tid & 63;
  const int wr = wave >> 1, wc = wave & 1;
  const int llo = lane & 15, lhi = lane >> 4;
  #pragma unroll
  for (int i = 0; i < 4; ++i)
    #pragma unroll
    for (int j = 0; j < 4; ++j) {
      int n = bcol + wc * 64 + j * 16 + llo;
      #pragma unroll
      for (int r = 0; r < 4; ++r) {
        int m = brow + wr * 64 + i * 16 + lhi * 4 + r;
        C[(size_t)m * DM_ + n] = acc[i][j][r];
      }
    }
}

// ---------------- flash attention (causal) ----------------
// grid: (T/64, BH). block: 256 (4 waves), wave w owns q rows q0+16w .. +15.
__global__ __launch_bounds__(256) void k_attn(
    const __hip_bfloat16* __restrict__ Q, const __hip_bfloat16* __restrict__ Kk,
    const __hip_bfloat16* __restrict__ VT, __hip_bfloat16* __restrict__ Y) {
  alignas(16) __shared__ __hip_bfloat16 Ks[64 * 64];
  alignas(16) __shared__ __hip_bfloat16 Vs[64 * 64];   // [dh][t']
  alignas(16) __shared__ __hip_bfloat16 Ps[4][16 * 64];
  const int bh = blockIdx.y, qt = blockIdx.x;
  const int q0 = qt * 64;
  const int tid = threadIdx.x, wave = tid >> 6, lane = tid & 63;
  const int llo = lane & 15, lhi = lane >> 4;
  const int qbase = q0 + wave * 16;

  bf16x8 aq[2];
  #pragma unroll
  for (int k0 = 0; k0 < 2; ++k0)
    aq[k0] = *reinterpret_cast<const bf16x8*>(
        Q + ((size_t)bh * T_ + qbase + llo) * DH_ + k0 * 32 + lhi * 8);

  float mrow[4], lrow[4];
  f32x4 o[4] = {};
  #pragma unroll
  for (int r = 0; r < 4; ++r) { mrow[r] = -INFINITY; lrow[r] = 0.f; }

  for (int t0 = 0; t0 <= q0; t0 += 64) {
    // stage K tile [64][64] and V^T tile [64 dh][64 t']
    #pragma unroll
    for (int p = 0; p < 2; ++p) {
      int rb = p * 32 + wave * 8;
      gload_lds16(Kk + ((size_t)bh * T_ + t0 + rb + (lane >> 3)) * DH_ + (lane & 7) * 8,
                  Ks + rb * 64);
      gload_lds16(VT + ((size_t)bh * DH_ + rb + (lane >> 3)) * T_ + t0 + (lane & 7) * 8,
                  Vs + rb * 64);
    }
    __syncthreads();

    // S = Q K^T
    f32x4 s[4];
    #pragma unroll
    for (int jn = 0; jn < 4; ++jn) {
      f32x4 z = {};
      bf16x8 b0 = *reinterpret_cast<const bf16x8*>(Ks + (jn * 16 + llo) * 64 + lhi * 8);
      bf16x8 b1 = *reinterpret_cast<const bf16x8*>(Ks + (jn * 16 + llo) * 64 + 32 + lhi * 8);
      z = __builtin_amdgcn_mfma_f32_16x16x32_bf16(aq[0], b0, z, 0, 0, 0);
      z = __builtin_amdgcn_mfma_f32_16x16x32_bf16(aq[1], b1, z, 0, 0, 0);
      s[jn] = z;
    }
    // scale + causal mask
    #pragma unroll
    for (int jn = 0; jn < 4; ++jn)
      #pragma unroll
      for (int r = 0; r < 4; ++r) {
        int qrow = qbase + lhi * 4 + r;
        int tcol = t0 + jn * 16 + llo;
        float v = s[jn][r] * 0.125f;
        s[jn][r] = (tcol <= qrow) ? v : -INFINITY;
      }
    // online softmax (per-row reduce across the 16-lane group)
    float alpha[4];
    #pragma unroll
    for (int r = 0; r < 4; ++r) {
      float mt = fmaxf(fmaxf(s[0][r], s[1][r]), fmaxf(s[2][r], s[3][r]));
      #pragma unroll
      for (int d = 1; d < 16; d <<= 1) mt = fmaxf(mt, __shfl_xor(mt, d));
      float mn = fmaxf(mrow[r], mt);
      alpha[r] = __expf(mrow[r] - mn);
      mrow[r] = mn;
    }
    float psum[4] = {0.f, 0.f, 0.f, 0.f};
    #pragma unroll
    for (int jn = 0; jn < 4; ++jn)
      #pragma unroll
      for (int r = 0; r < 4; ++r) {
        float p = __expf(s[jn][r] - mrow[r]);
        psum[r] += p;
        Ps[wave][(lhi * 4 + r) * 64 + jn * 16 + llo] = __float2bfloat16(p);
      }
    #pragma unroll
    for (int r = 0; r < 4; ++r) {
      float ps = psum[r];
      #pragma unroll
      for (int d = 1; d < 16; d <<= 1) ps += __shfl_xor(ps, d);
      lrow[r] = lrow[r] * alpha[r] + ps;
      #pragma unroll
      for (int jd = 0; jd < 4; ++jd) o[jd][r] *= alpha[r];
    }
    // PV: A = P (through per-wave LDS), B = V via V^T rows
    bf16x8 ap0 = *reinterpret_cast<const bf16x8*>(&Ps[wave][llo * 64 + lhi * 8]);
    bf16x8 ap1 = *reinterpret_cast<const bf16x8*>(&Ps[wave][llo * 64 + 32 + lhi * 8]);
    #pragma unroll
    for (int jd = 0; jd < 4; ++jd) {
      bf16x8 b0 = *reinterpret_cast<const bf16x8*>(Vs + (jd * 16 + llo) * 64 + lhi * 8);
      bf16x8 b1 = *reinterpret_cast<const bf16x8*>(Vs + (jd * 16 + llo) * 64 + 32 + lhi * 8);
      o[jd] = __builtin_amdgcn_mfma_f32_16x16x32_bf16(ap0, b0, o[jd], 0, 0, 0);
      o[jd] = __builtin_amdgcn_mfma_f32_16x16x32_bf16(ap1, b1, o[jd], 0, 0, 0);
    }
    __syncthreads();
  }

  // epilogue: y[b][t][h*64+dh]
  const int b = bh >> 4, h = bh & 15;
  #pragma unroll
  for (int jd = 0; jd < 4; ++jd)
    #pragma unroll
    for (int r = 0; r < 4; ++r) {
      int trow = qbase + lhi * 4 + r;
      int col = h * 64 + jd * 16 + llo;
      Y[((size_t)(b * T_ + trow)) * DM_ + col] = __float2bfloat16(o[jd][r] / lrow[r]);
    }
}

// ---------------- launch ----------------
extern "C" void kernel_launch(void* const* d_in, const int* in_sizes, int n_in,
                              void* d_out, int out_size, void* d_ws, size_t ws_size,
                              hipStream_t stream) {
  const float* x     = (const float*)d_in[0];
  const float* w_qkv = (const float*)d_in[1];
  const float* w_out = (const float*)d_in[2];
  float* out = (float*)d_out;
  char* ws = (char*)d_ws;

  size_t off = 0;
  __hip_bfloat16* xb    = (__hip_bfloat16*)(ws + off); off += (size_t)M_ * DM_ * 2;      // 8 MiB
  __hip_bfloat16* wqkvT = (__hip_bfloat16*)(ws + off); off += (size_t)3 * DM_ * DM_ * 2; // 6 MiB
  __hip_bfloat16* woutT = (__hip_bfloat16*)(ws + off); off += (size_t)DM_ * DM_ * 2;     // 2 MiB
  __hip_bfloat16* q_ws  = (__hip_bfloat16*)(ws + off); off += (size_t)M_ * DM_ * 2;      // 8 MiB
  __hip_bfloat16* k_ws  = (__hip_bfloat16*)(ws + off); off += (size_t)M_ * DM_ * 2;      // 8 MiB
  __hip_bfloat16* vtmp  = (__hip_bfloat16*)(ws + off); off += (size_t)M_ * DM_ * 2;      // 8 MiB
  __hip_bfloat16* vT    = (__hip_bfloat16*)(ws + off); off += (size_t)M_ * DM_ * 2;      // 8 MiB
  __hip_bfloat16* y_ws  = (__hip_bfloat16*)(ws + off); off += (size_t)M_ * DM_ * 2;      // 8 MiB
  (void)ws_size; (void)in_sizes; (void)n_in; (void)out_size;

  // convert inputs to bf16 (weights pre-transposed to B^T layout)
  k_cvt_bf16<<<(M_ * DM_ / 4 + 255) / 256, 256, 0, stream>>>(x, xb, M_ * DM_ / 4);
  k_cvtT<<<dim3(3 * DM_ / 32, DM_ / 32), 256, 0, stream>>>(w_qkv, wqkvT, DM_, 3 * DM_);
  k_cvtT<<<dim3(DM_ / 32, DM_ / 32), 256, 0, stream>>>(w_out, woutT, DM_, DM_);

  // qkv projection
  k_gemm_qkv<<<dim3(3 * DM_ / 128, M_ / 128), 256, 0, stream>>>(xb, wqkvT, q_ws, k_ws, vtmp);

  // V -> V^T per head
  k_transposeV<<<dim3(64, BH_), 256, 0, stream>>>(vtmp, vT);

  // causal flash attention
  k_attn<<<dim3(T_ / 64, BH_), 256, 0, stream>>>(q_ws, k_ws, vT, y_ws);

  // output projection (f32 out)
  k_gemm_out<<<dim3(DM_ / 128, M_ / 128), 256, 0, stream>>>(y_ws, woutT, out);
}